// Round 1
// baseline (1147.958 us; speedup 1.0000x reference)
//
#include <hip/hip_runtime.h>

#define BATCH_N   32768
#define IN_DIM    512
#define MID_N     512
#define NODES_N   1024
#define OUT_DIM   64

#define ROWS      64          // batch rows per block (lane = row)
#define TPB       512         // 8 waves
#define NWAVES    8
#define CPW       8           // columns per wave within a 64-node block
#define NBLK      8           // 512 mid nodes / 64
#define SIGPAD    513         // odd stride -> (lane+k)%32 banks, 2-way = free

// ---------------------------------------------------------------------------
// Kernel 1: eff = weight * connectivity  (f32, into workspace)
// ---------------------------------------------------------------------------
__global__ void prep_eff_kernel(const float4* __restrict__ w,
                                const int4* __restrict__ c,
                                float4* __restrict__ eff)
{
    const int i = blockIdx.x * 256 + threadIdx.x;   // grid sized exactly
    const int4 cv = c[i];
    const float4 wvv = w[i];
    float4 ev;
    ev.x = cv.x ? wvv.x : 0.0f;
    ev.y = cv.y ? wvv.y : 0.0f;
    ev.z = cv.z ? wvv.z : 0.0f;
    ev.w = cv.w ? wvv.w : 0.0f;
    eff[i] = ev;
}

// ---------------------------------------------------------------------------
// Kernel 2: fused GEMM + sequential sigmoid recurrence.
// Block: 64 batch rows, 8 waves. lane = row. Wave w owns cols [64b+8w, +8).
// sig[row][k] holds res_k (mid node k) for this block's 64 rows.
// ---------------------------------------------------------------------------
template<bool PRE>
__global__ __launch_bounds__(TPB, 2)
void nn_fused_kernel(const float* __restrict__ x,
                     const float* __restrict__ weight,
                     const float* __restrict__ bias,
                     const int* __restrict__ conn,
                     const int* __restrict__ ne,
                     const float* __restrict__ eff,
                     float* __restrict__ out)
{
    __shared__ float sig[ROWS][SIGPAD];

    const int tid  = threadIdx.x;
    const int wv   = tid >> 6;           // wave id 0..7
    const int lane = tid & 63;           // row within block
    const int r0   = blockIdx.x * ROWS;
    const int row  = r0 + lane;
    // wave id as a provably-uniform (SGPR) value so eff/bias addresses are
    // scalar -> s_load, and the eff value becomes the 1 allowed SGPR operand
    // of each v_fma_f32.
    const int wu   = __builtin_amdgcn_readfirstlane(wv);

    const float4* __restrict__ xr =
        reinterpret_cast<const float4*>(x + (size_t)row * IN_DIM);

    float acc[CPW];

    for (int b = 0; b < NBLK; ++b) {
        const int cbu = 64 * b + CPW * wu;        // uniform column base

        // ---------------- Phase A: dense accumulation -------------------
        #pragma unroll
        for (int c = 0; c < CPW; ++c) acc[c] = bias[cbu + c];

        // x contribution (node rows 0..511)
        #pragma unroll 2
        for (int k4 = 0; k4 < IN_DIM / 4; ++k4) {
            const float4 xv = xr[k4];
            #pragma unroll
            for (int j = 0; j < 4; ++j) {
                const int k = k4 * 4 + j;
                const float xs = (&xv.x)[j];
                const size_t ebase = (size_t)k * MID_N + cbu;
                #pragma unroll
                for (int c = 0; c < CPW; ++c) {
                    float e;
                    if constexpr (PRE) e = eff[ebase + c];
                    else e = conn[ebase + c] ? weight[ebase + c] : 0.0f;
                    acc[c] = fmaf(xs, e, acc[c]);
                }
            }
        }

        // res contribution (mid nodes 0 .. 64b-1), res read from LDS
        #pragma unroll 4
        for (int k = 0; k < 64 * b; ++k) {
            const float rv = sig[lane][k];
            const size_t ebase = (size_t)(IN_DIM + k) * MID_N + cbu;
            #pragma unroll
            for (int c = 0; c < CPW; ++c) {
                float e;
                if constexpr (PRE) e = eff[ebase + c];
                else e = conn[ebase + c] ? weight[ebase + c] : 0.0f;
                acc[c] = fmaf(rv, e, acc[c]);
            }
        }

        // ---------------- Phase B: sequential within the 64-node block ---
        for (int s = 0; s < NWAVES; ++s) {
            if (wv == s) {
                // owner wave: 8 sequential nodes, per-lane (per-row) private
                const int g0 = 64 * b + CPW * s;
                float rloc[CPW];
                #pragma unroll
                for (int j = 0; j < CPW; ++j) {
                    float z = acc[j];
                    #pragma unroll
                    for (int jj = 0; jj < CPW; ++jj) {
                        if (jj < j) {   // statically pruned by unroll
                            const size_t eo =
                                (size_t)(IN_DIM + g0 + jj) * MID_N + (g0 + j);
                            float e;
                            if constexpr (PRE) e = eff[eo];
                            else e = conn[eo] ? weight[eo] : 0.0f;
                            z = fmaf(rloc[jj], e, z);
                        }
                    }
                    const float ex = (ne[g0 + j] != 0) ? 1.0f : 0.0f;
                    const float r  = ex / (1.0f + __expf(-z));
                    rloc[j] = r;
                    sig[lane][g0 + j] = r;
                }
            }
            __syncthreads();
            if (wv > s) {
                // rank-8 update onto later columns of this node block
                const int g0 = 64 * b + CPW * s;
                #pragma unroll
                for (int jj = 0; jj < CPW; ++jj) {
                    const float rv = sig[lane][g0 + jj];
                    const size_t ebase = (size_t)(IN_DIM + g0 + jj) * MID_N + cbu;
                    #pragma unroll
                    for (int c = 0; c < CPW; ++c) {
                        float e;
                        if constexpr (PRE) e = eff[ebase + c];
                        else e = conn[ebase + c] ? weight[ebase + c] : 0.0f;
                        acc[c] = fmaf(rv, e, acc[c]);
                    }
                }
            }
        }
    }

    // ---------------- Output: res columns 448..511 -----------------------
    #pragma unroll
    for (int idx = tid; idx < ROWS * OUT_DIM; idx += TPB) {
        const int rr = idx >> 6;
        const int cc = idx & 63;
        out[(size_t)(r0 + rr) * OUT_DIM + cc] = sig[rr][(MID_N - OUT_DIM) + cc];
    }
}

// ---------------------------------------------------------------------------
extern "C" void kernel_launch(void* const* d_in, const int* in_sizes, int n_in,
                              void* d_out, int out_size, void* d_ws, size_t ws_size,
                              hipStream_t stream)
{
    const float* x      = (const float*)d_in[0];
    const float* weight = (const float*)d_in[1];
    const float* bias   = (const float*)d_in[2];
    const int*   conn   = (const int*)d_in[3];
    const int*   ne     = (const int*)d_in[4];
    float*       out    = (float*)d_out;

    const size_t eff_bytes = (size_t)NODES_N * MID_N * sizeof(float);
    const int    grid      = BATCH_N / ROWS;          // 512 blocks

    if (ws_size >= eff_bytes) {
        float* eff = (float*)d_ws;
        // 1024*512/4 = 131072 float4 elems = 512 blocks * 256 threads exactly
        prep_eff_kernel<<<512, 256, 0, stream>>>(
            (const float4*)weight, (const int4*)conn, (float4*)eff);
        nn_fused_kernel<true><<<grid, TPB, 0, stream>>>(
            x, weight, bias, conn, ne, eff, out);
    } else {
        nn_fused_kernel<false><<<grid, TPB, 0, stream>>>(
            x, weight, bias, conn, ne, nullptr, out);
    }
}

// Round 6
// 344.994 us; speedup vs baseline: 3.3275x; 3.3275x over previous
//
#include <hip/hip_runtime.h>

#define BATCH_N   32768
#define IN_DIM    512
#define MID_N     512
#define NODES_N   1024
#define OUT_DIM   64

#define ROWS      64          // batch rows per block (lane = row in phase B)
#define TPB       512         // 8 waves
#define NWAVES    8
#define NBLK      8           // 512 mid nodes / 64
#define SIGPAD    513         // round-1 fallback layout
#define SIG_STRIDE 456        // 448 used cols + 8 pad; row stride 912B = 57*16B
#define RESF_PAD  65

typedef __attribute__((ext_vector_type(8))) short          short8;
typedef __attribute__((ext_vector_type(8))) unsigned short ush8;
typedef __attribute__((ext_vector_type(4))) float          f32x4;

__device__ __forceinline__ unsigned short f2bf(float f) {
    unsigned u = __float_as_uint(f);
    return (unsigned short)((u + 0x7FFFu + ((u >> 16) & 1u)) >> 16);
}
__device__ __forceinline__ float bf2f(unsigned short h) {
    return __uint_as_float(((unsigned)h) << 16);
}

// 3-term hi/lo product: (ah+al)*(bh+bl) ~= al*bh + ah*bl + ah*bh
__device__ __forceinline__ f32x4 mfma3(short8 ah, short8 al, short8 bh, short8 bl, f32x4 c) {
    c = __builtin_amdgcn_mfma_f32_16x16x32_bf16(al, bh, c, 0, 0, 0);
    c = __builtin_amdgcn_mfma_f32_16x16x32_bf16(ah, bl, c, 0, 0, 0);
    c = __builtin_amdgcn_mfma_f32_16x16x32_bf16(ah, bh, c, 0, 0, 0);
    return c;
}

// ---------------------------------------------------------------------------
// Prep 1: effF = weight * connectivity (fp32, plain [1024][512])
// ---------------------------------------------------------------------------
__global__ void prep_eff_kernel(const float4* __restrict__ w,
                                const int4* __restrict__ c,
                                float4* __restrict__ eff)
{
    const int i = blockIdx.x * 256 + threadIdx.x;
    const int4 cv = c[i];
    const float4 wvv = w[i];
    float4 ev;
    ev.x = cv.x ? wvv.x : 0.0f;
    ev.y = cv.y ? wvv.y : 0.0f;
    ev.z = cv.z ? wvv.z : 0.0f;
    ev.w = cv.w ? wvv.w : 0.0f;
    eff[i] = ev;
}

// ---------------------------------------------------------------------------
// Prep 2: effB hi/lo, B-fragment order. Frag(kt 0..31, ct 0..31):
//   lane l holds B[k=kt*32+8*(l>>4)+j][col=ct*16+(l&15)], j=0..7, 16B/lane.
// (Any bijective per-lane k-permutation works as long as A uses the same.)
// ---------------------------------------------------------------------------
__global__ void prep_effB_kernel(const float* __restrict__ effF,
                                 unsigned short* __restrict__ ebh,
                                 unsigned short* __restrict__ ebl)
{
    const int t    = blockIdx.x * 256 + threadIdx.x;  // 32*32*64 = 65536 total
    const int lane = t & 63;
    const int ct   = (t >> 6) & 31;
    const int kt   = t >> 11;
    const int col  = ct * 16 + (lane & 15);
    const int k0   = kt * 32 + 8 * (lane >> 4);
    ush8 h, l;
    #pragma unroll
    for (int j = 0; j < 8; ++j) {
        float e = effF[(size_t)(k0 + j) * MID_N + col];
        unsigned short hb = f2bf(e);
        h[j] = hb;
        l[j] = f2bf(e - bf2f(hb));
    }
    *(ush8*)&ebh[(size_t)t * 8] = h;
    *(ush8*)&ebl[(size_t)t * 8] = l;
}

// ---------------------------------------------------------------------------
// Prep 3: x hi/lo, A-fragment order. Frag(rt 0..2047, kt 0..15):
//   lane l holds x[row=rt*16+(l&15)][k=kt*32+8*(l>>4)+j], j=0..7, 16B/lane.
// ---------------------------------------------------------------------------
__global__ void prep_x_kernel(const float* __restrict__ x,
                              unsigned short* __restrict__ xfh,
                              unsigned short* __restrict__ xfl)
{
    const int t    = blockIdx.x * 256 + threadIdx.x;  // 2048*16*64 = 2,097,152
    const int lane = t & 63;
    const int kt   = (t >> 6) & 15;
    const int rt   = t >> 10;
    const int row  = rt * 16 + (lane & 15);
    const int k0   = kt * 32 + 8 * (lane >> 4);
    const float4* xp = (const float4*)(x + (size_t)row * IN_DIM + k0);
    const float4 v0 = xp[0];
    const float4 v1 = xp[1];
    const float vv[8] = {v0.x, v0.y, v0.z, v0.w, v1.x, v1.y, v1.z, v1.w};
    ush8 h, l;
    #pragma unroll
    for (int j = 0; j < 8; ++j) {
        unsigned short hb = f2bf(vv[j]);
        h[j] = hb;
        l[j] = f2bf(vv[j] - bf2f(hb));
    }
    *(ush8*)&xfh[(size_t)t * 8] = h;
    *(ush8*)&xfl[(size_t)t * 8] = l;
}

// ---------------------------------------------------------------------------
// Main: per block 64 batch rows. 8 waves; wave w owns node-block w's
// 64x64 accumulator (4x4 tiles of 16x16 MFMA). Dense K=512 via MFMA,
// cross-block res contributions via MFMA from LDS (hi/lo bf16 history),
// within-64-node sequential part = round-1 VALU phase B.
// ---------------------------------------------------------------------------
__global__ __launch_bounds__(TPB, 2)
void nn_mfma_kernel(const float* __restrict__ bias,
                    const int* __restrict__ ne,
                    const float* __restrict__ effF,
                    const unsigned short* __restrict__ xfh,
                    const unsigned short* __restrict__ xfl,
                    const unsigned short* __restrict__ ebh,
                    const unsigned short* __restrict__ ebl,
                    float* __restrict__ out)
{
    __shared__ unsigned short sig_hi[ROWS][SIG_STRIDE];
    __shared__ unsigned short sig_lo[ROWS][SIG_STRIDE];
    __shared__ float resf[ROWS][RESF_PAD];    // z-dump / res buffer

    const int tid  = threadIdx.x;
    const int wv   = tid >> 6;
    const int lane = tid & 63;
    const int l15  = lane & 15;
    const int lg   = lane >> 4;
    const int bl   = blockIdx.x;
    const int r0   = bl * ROWS;

    const short8* XFH = (const short8*)xfh;
    const short8* XFL = (const short8*)xfl;
    const short8* EBH = (const short8*)ebh;
    const short8* EBL = (const short8*)ebl;

    f32x4 acc[4][4];
    #pragma unroll
    for (int ct = 0; ct < 4; ++ct) {
        const float bv = bias[64 * wv + 16 * ct + l15];
        #pragma unroll
        for (int rt = 0; rt < 4; ++rt) {
            acc[rt][ct][0] = bv; acc[rt][ct][1] = bv;
            acc[rt][ct][2] = bv; acc[rt][ct][3] = bv;
        }
    }

    // ---------------- dense: z += x @ effTop (K = 512) --------------------
    #pragma unroll 1
    for (int kt = 0; kt < 16; ++kt) {
        short8 ah[4], al[4], bh[4], blo[4];
        #pragma unroll
        for (int rt = 0; rt < 4; ++rt) {
            const size_t f = ((size_t)(bl * 4 + rt) * 16 + kt) * 64 + lane;
            ah[rt] = XFH[f];
            al[rt] = XFL[f];
        }
        #pragma unroll
        for (int ct = 0; ct < 4; ++ct) {
            const size_t f = ((size_t)kt * 32 + (4 * wv + ct)) * 64 + lane;
            bh[ct]  = EBH[f];
            blo[ct] = EBL[f];
        }
        #pragma unroll
        for (int rt = 0; rt < 4; ++rt)
            #pragma unroll
            for (int ct = 0; ct < 4; ++ct)
                acc[rt][ct] = mfma3(ah[rt], al[rt], bh[ct], blo[ct], acc[rt][ct]);
    }

    // ---------------- recurrence over 8 node blocks -----------------------
    #pragma unroll 1
    for (int b = 0; b < NBLK; ++b) {
        // wave b dumps its (now final) 64x64 z to LDS
        if (wv == b) {
            #pragma unroll
            for (int rt = 0; rt < 4; ++rt)
                #pragma unroll
                for (int ct = 0; ct < 4; ++ct)
                    #pragma unroll
                    for (int r = 0; r < 4; ++r)
                        resf[16 * rt + 4 * lg + r][16 * ct + l15] = acc[rt][ct][r];
        }
        __syncthreads();

        // every wave grabs z for its 8 owned cols (lane = row)
        float zreg[8];
        #pragma unroll
        for (int j = 0; j < 8; ++j) zreg[j] = resf[lane][8 * wv + j];
        __syncthreads();

        const int g0w = 64 * b + 8 * wv;   // this wave's global col base

        for (int s = 0; s < NWAVES; ++s) {
            if (wv == s) {
                // owner: 8 sequential sigmoid nodes (fp32, round-1 math)
                float rloc[8];
                #pragma unroll
                for (int j = 0; j < 8; ++j) {
                    float z = zreg[j];
                    #pragma unroll
                    for (int jj = 0; jj < 8; ++jj) {
                        if (jj < j) {
                            const size_t eo =
                                (size_t)(IN_DIM + g0w + jj) * MID_N + (g0w + j);
                            z = fmaf(rloc[jj], effF[eo], z);
                        }
                    }
                    const float ex = (ne[g0w + j] != 0) ? 1.0f : 0.0f;
                    const float r  = ex / (1.0f + __expf(-z));
                    rloc[j] = r;
                    resf[lane][8 * wv + j] = r;
                }
            }
            __syncthreads();
            if (wv > s) {
                // rank-8 update onto this wave's 8 cols
                const int ks = 64 * b + 8 * s;
                #pragma unroll
                for (int jj = 0; jj < 8; ++jj) {
                    const float rv = resf[lane][8 * s + jj];
                    const size_t eb = (size_t)(IN_DIM + ks + jj) * MID_N + g0w;
                    #pragma unroll
                    for (int c = 0; c < 8; ++c)
                        zreg[c] = fmaf(rv, effF[eb + c], zreg[c]);
                }
            }
        }
        __syncthreads();

        if (b < 7) {
            // convert res block -> bf16 hi/lo history (A-readable layout)
            const int row = tid >> 3;
            const int c0  = (tid & 7) * 8;
            ush8 h, l;
            #pragma unroll
            for (int j = 0; j < 8; ++j) {
                const float v = resf[row][c0 + j];
                unsigned short hb = f2bf(v);
                h[j] = hb;
                l[j] = f2bf(v - bf2f(hb));
            }
            *(ush8*)&sig_hi[row][64 * b + c0] = h;
            *(ush8*)&sig_lo[row][64 * b + c0] = l;
        } else {
            // final block's res IS the output (cols 448..511)
            #pragma unroll
            for (int p = 0; p < 8; ++p) {
                const int idx = tid + p * TPB;
                out[(size_t)(r0 + (idx >> 6)) * OUT_DIM + (idx & 63)] =
                    resf[idx >> 6][idx & 63];
            }
        }
        __syncthreads();

        if (b < 7 && wv > b) {
            // cross-update: acc += res_b @ eff[512+64b .., own cols] (K=64)
            #pragma unroll
            for (int kk = 0; kk < 2; ++kk) {
                short8 ah[4], al[4];
                const int kb = 64 * b + 32 * kk + 8 * lg;
                #pragma unroll
                for (int rt = 0; rt < 4; ++rt) {
                    const int rr = 16 * rt + l15;
                    ah[rt] = *(const short8*)&sig_hi[rr][kb];
                    al[rt] = *(const short8*)&sig_lo[rr][kb];
                }
                #pragma unroll
                for (int ct = 0; ct < 4; ++ct) {
                    const size_t f =
                        ((size_t)(16 + 2 * b + kk) * 32 + (4 * wv + ct)) * 64 + lane;
                    const short8 bh  = EBH[f];
                    const short8 blo = EBL[f];
                    #pragma unroll
                    for (int rt = 0; rt < 4; ++rt)
                        acc[rt][ct] = mfma3(ah[rt], al[rt], bh, blo, acc[rt][ct]);
                }
            }
        }
    }
}

// ---------------------------------------------------------------------------
// Round-1 fallback (proven correct) for small ws.
// ---------------------------------------------------------------------------
template<bool PRE>
__global__ __launch_bounds__(TPB, 2)
void nn_fused_kernel(const float* __restrict__ x,
                     const float* __restrict__ weight,
                     const float* __restrict__ bias,
                     const int* __restrict__ conn,
                     const int* __restrict__ ne,
                     const float* __restrict__ eff,
                     float* __restrict__ out)
{
    __shared__ float sig[ROWS][SIGPAD];
    const int tid  = threadIdx.x;
    const int wv   = tid >> 6;
    const int lane = tid & 63;
    const int r0   = blockIdx.x * ROWS;
    const int row  = r0 + lane;
    const int wu   = __builtin_amdgcn_readfirstlane(wv);
    const float4* __restrict__ xr =
        reinterpret_cast<const float4*>(x + (size_t)row * IN_DIM);
    float acc[8];

    for (int b = 0; b < NBLK; ++b) {
        const int cbu = 64 * b + 8 * wu;
        #pragma unroll
        for (int c = 0; c < 8; ++c) acc[c] = bias[cbu + c];
        #pragma unroll 2
        for (int k4 = 0; k4 < IN_DIM / 4; ++k4) {
            const float4 xv = xr[k4];
            #pragma unroll
            for (int j = 0; j < 4; ++j) {
                const int k = k4 * 4 + j;
                const float xs = (&xv.x)[j];
                const size_t ebase = (size_t)k * MID_N + cbu;
                #pragma unroll
                for (int c = 0; c < 8; ++c) {
                    float e;
                    if constexpr (PRE) e = eff[ebase + c];
                    else e = conn[ebase + c] ? weight[ebase + c] : 0.0f;
                    acc[c] = fmaf(xs, e, acc[c]);
                }
            }
        }
        #pragma unroll 4
        for (int k = 0; k < 64 * b; ++k) {
            const float rv = sig[lane][k];
            const size_t ebase = (size_t)(IN_DIM + k) * MID_N + cbu;
            #pragma unroll
            for (int c = 0; c < 8; ++c) {
                float e;
                if constexpr (PRE) e = eff[ebase + c];
                else e = conn[ebase + c] ? weight[ebase + c] : 0.0f;
                acc[c] = fmaf(rv, e, acc[c]);
            }
        }
        for (int s = 0; s < NWAVES; ++s) {
            if (wv == s) {
                const int g0 = 64 * b + 8 * s;
                float rloc[8];
                #pragma unroll
                for (int j = 0; j < 8; ++j) {
                    float z = acc[j];
                    #pragma unroll
                    for (int jj = 0; jj < 8; ++jj) {
                        if (jj < j) {
                            const size_t eo =
                                (size_t)(IN_DIM + g0 + jj) * MID_N + (g0 + j);
                            float e;
                            if constexpr (PRE) e = eff[eo];
                            else e = conn[eo] ? weight[eo] : 0.0f;
                            z = fmaf(rloc[jj], e, z);
                        }
                    }
                    const float ex = (ne[g0 + j] != 0) ? 1.0f : 0.0f;
                    const float r  = ex / (1.0f + __expf(-z));
                    rloc[j] = r;
                    sig[lane][g0 + j] = r;
                }
            }
            __syncthreads();
            if (wv > s) {
                const int g0 = 64 * b + 8 * s;
                #pragma unroll
                for (int jj = 0; jj < 8; ++jj) {
                    const float rv = sig[lane][g0 + jj];
                    const size_t ebase = (size_t)(IN_DIM + g0 + jj) * MID_N + cbu;
                    #pragma unroll
                    for (int c = 0; c < 8; ++c) {
                        float e;
                        if constexpr (PRE) e = eff[ebase + c];
                        else e = conn[ebase + c] ? weight[ebase + c] : 0.0f;
                        acc[c] = fmaf(rv, e, acc[c]);
                    }
                }
            }
        }
    }
    #pragma unroll
    for (int idx = tid; idx < ROWS * OUT_DIM; idx += TPB) {
        const int rr = idx >> 6;
        const int cc = idx & 63;
        out[(size_t)(r0 + rr) * OUT_DIM + cc] = sig[rr][(MID_N - OUT_DIM) + cc];
    }
}

// ---------------------------------------------------------------------------
extern "C" void kernel_launch(void* const* d_in, const int* in_sizes, int n_in,
                              void* d_out, int out_size, void* d_ws, size_t ws_size,
                              hipStream_t stream)
{
    const float* x      = (const float*)d_in[0];
    const float* weight = (const float*)d_in[1];
    const float* bias   = (const float*)d_in[2];
    const int*   conn   = (const int*)d_in[3];
    const int*   ne     = (const int*)d_in[4];
    float*       out    = (float*)d_out;

    // ws layout
    const size_t effF_b = (size_t)NODES_N * MID_N * sizeof(float);      // 2 MiB
    const size_t ebh_b  = (size_t)32 * 32 * 64 * 8 * 2;                 // 1 MiB
    const size_t xfh_b  = (size_t)2048 * 16 * 64 * 8 * 2;               // 32 MiB
    const size_t need   = effF_b + 2 * ebh_b + 2 * xfh_b;               // 68 MiB

    if (ws_size >= need) {
        char* w0 = (char*)d_ws;
        float*          effF = (float*)w0;
        unsigned short* ebh  = (unsigned short*)(w0 + effF_b);
        unsigned short* ebl  = (unsigned short*)(w0 + effF_b + ebh_b);
        unsigned short* xfh  = (unsigned short*)(w0 + effF_b + 2 * ebh_b);
        unsigned short* xfl  = (unsigned short*)(w0 + effF_b + 2 * ebh_b + xfh_b);

        prep_eff_kernel<<<512, 256, 0, stream>>>(
            (const float4*)weight, (const int4*)conn, (float4*)effF);
        prep_effB_kernel<<<256, 256, 0, stream>>>(effF, ebh, ebl);
        prep_x_kernel<<<8192, 256, 0, stream>>>(x, xfh, xfl);
        nn_mfma_kernel<<<BATCH_N / ROWS, TPB, 0, stream>>>(
            bias, ne, effF, xfh, xfl, ebh, ebl, out);
    } else if (ws_size >= effF_b) {
        float* eff = (float*)d_ws;
        prep_eff_kernel<<<512, 256, 0, stream>>>(
            (const float4*)weight, (const int4*)conn, (float4*)eff);
        nn_fused_kernel<true><<<BATCH_N / ROWS, TPB, 0, stream>>>(
            x, weight, bias, conn, ne, eff, out);
    } else {
        nn_fused_kernel<false><<<BATCH_N / ROWS, TPB, 0, stream>>>(
            x, weight, bias, conn, ne, nullptr, out);
    }
}